// Round 10
// baseline (267.420 us; speedup 1.0000x reference)
//
#include <hip/hip_runtime.h>

// ---------------------------------------------------------------------------
// GIN: 3 x (gather-sum + (x+agg)@W + b, relu) + MLP head, bf16 MFMA.
// r10: UN-FUSE gather from GEMM. The fused kernels pinned the latency-bound
// gather at 12 waves/CU (LDS 34KB + VGPR 112 + grid 782). Now:
//  - agg_kernel: 1 node / 16-lane group, 3125 blocks, ZERO LDS, 2x8-batch
//    branch-free slot gather -> 24-32 waves/CU of pure load parallelism.
//  - LDS-free MFMA GEMMs (A-frags from global) - memory-bound, ~8us each.
//  - head: one fused 2-stage GEMM block (r2 shape).
// 10 dispatches: prep, bin, sort, 3x(agg, gemm), head.
// ---------------------------------------------------------------------------

typedef short short8 __attribute__((ext_vector_type(8)));
typedef float v4f __attribute__((ext_vector_type(4)));

#define BCAP 1024   // per-64-node-bucket edge capacity (avg 768, +9 sigma)
#define MAXB 1024   // >= nbuckets (782)

__device__ inline unsigned short f2bf(float f) {
  union { float f; unsigned int u; } c; c.f = f;
  unsigned int u = c.u;
  return (unsigned short)((u + 0x7fffu + ((u >> 16) & 1u)) >> 16);  // RNE
}
__device__ inline float bfbits2f(unsigned int hi) {
  union { unsigned int u; float f; } c; c.u = hi; return c.f;
}
__device__ inline unsigned int pack2(float a, float b) {
  return (unsigned int)f2bf(a) | ((unsigned int)f2bf(b) << 16);
}
__device__ inline void add8(float* s, uint4 v) {
  s[0] += bfbits2f(v.x << 16); s[1] += bfbits2f(v.x & 0xffff0000u);
  s[2] += bfbits2f(v.y << 16); s[3] += bfbits2f(v.y & 0xffff0000u);
  s[4] += bfbits2f(v.z << 16); s[5] += bfbits2f(v.z & 0xffff0000u);
  s[6] += bfbits2f(v.w << 16); s[7] += bfbits2f(v.w & 0xffff0000u);
}
__device__ inline int wave_incl_scan_int(int v, int lane) {
#pragma unroll
  for (int off = 1; off < 64; off <<= 1) {
    int t = __shfl_up(v, off, 64);
    if (lane >= off) v += t;
  }
  return v;
}

// ------------------------- prep: weights + x->bf16 + zero rows/bcnt ---------
__global__ __launch_bounds__(256) void prep_all(
    const float* __restrict__ W0, const float* __restrict__ W1, const float* __restrict__ W2,
    const float* __restrict__ Wm1, const float* __restrict__ Wm2,
    unsigned short* __restrict__ W0T, unsigned short* __restrict__ W1T,
    unsigned short* __restrict__ W2T, unsigned short* __restrict__ Wm1T,
    unsigned short* __restrict__ Wm2T,
    const float* __restrict__ x, unsigned short* __restrict__ xb, int n8,
    int* __restrict__ bcnt, unsigned short* __restrict__ h1,
    unsigned short* __restrict__ h2, int N) {
  int i = blockIdx.x * 256 + threadIdx.x;
  if (i < MAXB) bcnt[i] = 0;
  if (blockIdx.x == 0) {  // zero dummy row N of gather inputs xb/h1/h2
    int t = threadIdx.x;
    uint4 z = make_uint4(0, 0, 0, 0);
    if (t < 16)            ((uint4*)xb)[(size_t)N * 16 + t] = z;
    else if (t < 32)       ((uint4*)h1)[(size_t)N * 16 + (t - 16)] = z;
    else if (t < 48)       ((uint4*)h2)[(size_t)N * 16 + (t - 32)] = z;
  }
  if (i < n8) {
    const float4* p = (const float4*)x;
    float4 a = p[2 * (size_t)i], b = p[2 * (size_t)i + 1];
    uint4 o;
    o.x = pack2(a.x, a.y); o.y = pack2(a.z, a.w);
    o.z = pack2(b.x, b.y); o.w = pack2(b.z, b.w);
    ((uint4*)xb)[i] = o;
  }
  if (i < 49152) {                       // 3 x [128,128] -> [128n][128k]
    int w = i / 16384, r = i % 16384;
    int nn = r >> 7, k = r & 127;
    const float* W = (w == 0) ? W0 : (w == 1) ? W1 : W2;
    unsigned short* O = (w == 0) ? W0T : (w == 1) ? W1T : W2T;
    O[r] = f2bf(W[k * 128 + nn]);
  } else if (i < 49152 + 32768) {        // Wm1 [128,256] -> [256n][128k]
    int r = i - 49152;
    int nn = r >> 7, k = r & 127;
    Wm1T[r] = f2bf(Wm1[k * 256 + nn]);
  } else if (i < 49152 + 32768 + 4096) { // Wm2 [256,10] -> [16n][256k], pad 0
    int r = i - 49152 - 32768;
    int nn = r >> 8, k = r & 255;
    Wm2T[r] = (nn < 10) ? f2bf(Wm2[k * 10 + nn]) : (unsigned short)0;
  }
}

// ------------------------- bin edges into 64-node buckets -------------------
__global__ __launch_bounds__(256) void bin_edges(
    const int* __restrict__ src, const int* __restrict__ dst, int E, int per,
    int* __restrict__ bcnt, int* __restrict__ bucketA, int nbuckets) {
  __shared__ int hist[MAXB];
  __shared__ int base[MAXB];
  const int tid = threadIdx.x;
  const int e0 = blockIdx.x * per;
  const int e1 = (e0 + per < E) ? e0 + per : E;
  for (int j = tid; j < nbuckets; j += 256) hist[j] = 0;
  __syncthreads();
  for (int i = e0 + tid; i < e1; i += 256) atomicAdd(&hist[dst[i] >> 6], 1);
  __syncthreads();
  for (int j = tid; j < nbuckets; j += 256) {
    int h = hist[j];
    base[j] = h ? atomicAdd(&bcnt[j], h) : 0;
  }
  __syncthreads();
  for (int i = e0 + tid; i < e1; i += 256) {
    int d = dst[i], s = src[i];
    int b = d >> 6;
    int r = atomicAdd(&base[b], 1);
    bucketA[(size_t)b * BCAP + r] = (s << 6) | (d & 63);
  }
}

// ------------------------- per-bucket sort + padded slots + deg/ebeg --------
__global__ __launch_bounds__(256) void sort_buckets(
    const int* __restrict__ bcnt, const int* __restrict__ bucketA,
    int* __restrict__ srcsS, int* __restrict__ srcsPad,
    int* __restrict__ degE, int* __restrict__ ebegA, int N) {
  __shared__ int rawE[BCAP], sortedS[BCAP];
  __shared__ int hist[64], cur[64], offs[65];
  const int tid = threadIdx.x;
  const int b = blockIdx.x;
  const int blk = b * 64;
  const int cnt = bcnt[b];
  for (int i = tid; i < cnt; i += 256) rawE[i] = bucketA[(size_t)b * BCAP + i];
  if (tid < 64) hist[tid] = 0;
  __syncthreads();
  for (int i = tid; i < cnt; i += 256) atomicAdd(&hist[rawE[i] & 63], 1);
  __syncthreads();
  if (tid < 64) {
    int v = hist[tid];
    int incl = wave_incl_scan_int(v, tid);
    offs[tid] = incl - v;
    cur[tid] = incl - v;
    if (tid == 63) offs[64] = incl;
  }
  __syncthreads();
  for (int i = tid; i < cnt; i += 256) {
    int e = rawE[i];
    int p = atomicAdd(&cur[e & 63], 1);
    sortedS[p] = e >> 6;
  }
  __syncthreads();
  for (int i = tid; i < cnt; i += 256) srcsS[(size_t)b * BCAP + i] = sortedS[i];
  if (tid < 64) {
    degE[blk + tid] = offs[tid + 1] - offs[tid];
    ebegA[blk + tid] = b * BCAP + offs[tid];
  }
  for (int idx = tid; idx < 1024; idx += 256) {
    int nl = idx >> 4, j = idx & 15;
    int beg = offs[nl], c = offs[nl + 1] - beg;
    srcsPad[((size_t)(blk + nl)) * 16 + j] = (j < c) ? sortedS[beg + j] : N;
  }
}

// ------------------------- standalone aggregation ---------------------------
// 1 node / 16-lane group; 16 nodes / 256-thr block; ZERO LDS.
// Per node: self + 16 padded slots (dummy -> zero row N) in two 8-batches,
// + rare overflow tail (deg > 16) from the sorted list.
__global__ __launch_bounds__(256) void agg_kernel(
    const uint4* __restrict__ X, const int* __restrict__ srcsPad,
    const int* __restrict__ srcsS, const int* __restrict__ degE,
    const int* __restrict__ ebegA, uint4* __restrict__ OUT, int N) {
  const int g = threadIdx.x >> 4, l = threadIdx.x & 15;
  const int node = blockIdx.x * 16 + g;
  if (node >= N) return;
  const int gb = (threadIdx.x & 63) & 48;
  const int myidx = srcsPad[(size_t)node * 16 + l];  // coalesced 64B/group
  const int c = degE[node];
  uint4 self = X[(size_t)node * 16 + l];
  float s[8] = {0, 0, 0, 0, 0, 0, 0, 0};

  uint4 r[8];
#pragma unroll
  for (int j = 0; j < 8; ++j) {
    int ij = __shfl(myidx, gb + j, 64);
    r[j] = X[(size_t)ij * 16 + l];
  }
  add8(s, self);
#pragma unroll
  for (int j = 0; j < 8; ++j) add8(s, r[j]);
#pragma unroll
  for (int j = 0; j < 8; ++j) {
    int ij = __shfl(myidx, gb + 8 + j, 64);
    r[j] = X[(size_t)ij * 16 + l];
  }
#pragma unroll
  for (int j = 0; j < 8; ++j) add8(s, r[j]);

  if (c > 16) {
    int eb = ebegA[node];
    for (int j = 16; j < c; ++j)
      add8(s, X[(size_t)srcsS[eb + j] * 16 + l]);
  }
  uint4 o;
  o.x = pack2(s[0], s[1]); o.y = pack2(s[2], s[3]);
  o.z = pack2(s[4], s[5]); o.w = pack2(s[6], s[7]);
  OUT[(size_t)node * 16 + l] = o;
}

// ------------------------- LDS-free MFMA GEMM (layers) ----------------------
// C[M,128] = relu(A[M,128] @ BT[128,128]^T + bias), bf16 in/out.
// Block 256 thr = 4 waves 2x2; block tile 64m x 128n; wave 32m x 64n.
__global__ __launch_bounds__(256) void gemm_relu(
    const unsigned short* __restrict__ A, const unsigned short* __restrict__ BT,
    const float* __restrict__ bias, unsigned short* __restrict__ C, int M) {
  const int tid = threadIdx.x;
  const int lane = tid & 63;
  const int w = tid >> 6;
  const int wm = w & 1, wn = w >> 1;
  const int l15 = lane & 15;
  const int quad = lane >> 4;
  const int m_base = blockIdx.x * 64 + wm * 32;
  const int n_base = wn * 64;
  const int koff = quad * 8;

  const unsigned short* ap[2];
#pragma unroll
  for (int mf = 0; mf < 2; ++mf) {
    int r = m_base + mf * 16 + l15;
    if (r > M - 1) r = M - 1;
    ap[mf] = A + (size_t)r * 128 + koff;
  }
  const unsigned short* bp[4];
#pragma unroll
  for (int nf = 0; nf < 4; ++nf)
    bp[nf] = BT + (size_t)(n_base + nf * 16 + l15) * 128 + koff;

  v4f acc[2][4];
#pragma unroll
  for (int mf = 0; mf < 2; ++mf)
#pragma unroll
    for (int nf = 0; nf < 4; ++nf) acc[mf][nf] = (v4f)0.f;

#pragma unroll
  for (int k0 = 0; k0 < 128; k0 += 32) {
    short8 a[2], b[4];
#pragma unroll
    for (int mf = 0; mf < 2; ++mf) a[mf] = *(const short8*)(ap[mf] + k0);
#pragma unroll
    for (int nf = 0; nf < 4; ++nf) b[nf] = *(const short8*)(bp[nf] + k0);
#pragma unroll
    for (int mf = 0; mf < 2; ++mf)
#pragma unroll
      for (int nf = 0; nf < 4; ++nf)
        acc[mf][nf] = __builtin_amdgcn_mfma_f32_16x16x32_bf16(a[mf], b[nf], acc[mf][nf], 0, 0, 0);
  }

#pragma unroll
  for (int mf = 0; mf < 2; ++mf) {
#pragma unroll
    for (int r = 0; r < 4; ++r) {
      int grow = m_base + mf * 16 + quad * 4 + r;
      if (grow >= M) continue;
#pragma unroll
      for (int nf = 0; nf < 4; ++nf) {
        int gcol = n_base + nf * 16 + l15;
        float v = acc[mf][nf][r] + bias[gcol];
        C[(size_t)grow * 128 + gcol] = f2bf(fmaxf(v, 0.f));
      }
    }
  }
}

// ------------------------- fused MLP head ----------------------------------
// Per 64-row block: Hs[64,256] = relu(A @ Wm1T^T + bm1) in LDS,
// then out[64,10] = Hs @ Wm2T^T + bm2 (Wm2T zero-padded to 16 cols).
__global__ __launch_bounds__(256) void fused_head(
    const unsigned short* __restrict__ A, const unsigned short* __restrict__ W1T,
    const float* __restrict__ b1, const unsigned short* __restrict__ W2T,
    const float* __restrict__ b2, float* __restrict__ out, int M, int NOUT) {
  __shared__ __align__(16) unsigned short Hs[64 * 264];  // 256 + 8 pad
  const int tid = threadIdx.x, lane = tid & 63, w = tid >> 6;
  const int l15 = lane & 15, quad = lane >> 4;
  const int blk = blockIdx.x * 64;

  const int wm = w & 1, wn = w >> 1;
  const int mb = wm * 32, nb = wn * 128;
  const unsigned short* ap[2];
#pragma unroll
  for (int mf = 0; mf < 2; ++mf) {
    int r = blk + mb + mf * 16 + l15;
    if (r > M - 1) r = M - 1;
    ap[mf] = A + (size_t)r * 128 + quad * 8;
  }
  v4f acc[2][8];
#pragma unroll
  for (int mf = 0; mf < 2; ++mf)
#pragma unroll
    for (int nf = 0; nf < 8; ++nf) acc[mf][nf] = (v4f)0.f;

#pragma unroll
  for (int k0 = 0; k0 < 128; k0 += 32) {
    short8 a[2];
#pragma unroll
    for (int mf = 0; mf < 2; ++mf) a[mf] = *(const short8*)(ap[mf] + k0);
#pragma unroll
    for (int nf = 0; nf < 8; ++nf) {
      short8 bb = *(const short8*)(W1T + (size_t)(nb + nf * 16 + l15) * 128 + quad * 8 + k0);
#pragma unroll
      for (int mf = 0; mf < 2; ++mf)
        acc[mf][nf] = __builtin_amdgcn_mfma_f32_16x16x32_bf16(a[mf], bb, acc[mf][nf], 0, 0, 0);
    }
  }
#pragma unroll
  for (int mf = 0; mf < 2; ++mf)
#pragma unroll
    for (int r = 0; r < 4; ++r) {
      int row = mb + mf * 16 + quad * 4 + r;
#pragma unroll
      for (int nf = 0; nf < 8; ++nf) {
        int col = nb + nf * 16 + l15;
        float v = acc[mf][nf][r] + b1[col];
        Hs[row * 264 + col] = f2bf(fmaxf(v, 0.f));
      }
    }
  __syncthreads();

  const int rowl = w * 16 + l15;
  const unsigned short* bp2 = W2T + (size_t)l15 * 256 + quad * 8;
  v4f acc2 = (v4f)0.f;
#pragma unroll
  for (int k0 = 0; k0 < 256; k0 += 32)
    acc2 = __builtin_amdgcn_mfma_f32_16x16x32_bf16(
        *(const short8*)&Hs[rowl * 264 + k0 + quad * 8],
        *(const short8*)(bp2 + k0), acc2, 0, 0, 0);
  float bb = (l15 < NOUT) ? b2[l15] : 0.f;
#pragma unroll
  for (int r = 0; r < 4; ++r) {
    int grow = blk + w * 16 + quad * 4 + r;
    if (grow < M && l15 < NOUT) out[(size_t)grow * NOUT + l15] = acc2[r] + bb;
  }
}

// ---------------------------------------------------------------------------

extern "C" void kernel_launch(void* const* d_in, const int* in_sizes, int n_in,
                              void* d_out, int out_size, void* d_ws, size_t ws_size,
                              hipStream_t stream) {
  const float* x   = (const float*)d_in[0];
  const int*   ei  = (const int*)d_in[1];
  const float* W0  = (const float*)d_in[2];
  const float* b0  = (const float*)d_in[3];
  const float* W1  = (const float*)d_in[4];
  const float* b1  = (const float*)d_in[5];
  const float* W2  = (const float*)d_in[6];
  const float* b2  = (const float*)d_in[7];
  const float* Wm1 = (const float*)d_in[8];
  const float* bm1 = (const float*)d_in[9];
  const float* Wm2 = (const float*)d_in[10];
  const float* bm2 = (const float*)d_in[11];
  float* out = (float*)d_out;

  const int D = 128;
  const int N = in_sizes[0] / D;   // 50000
  const int E = in_sizes[1] / 2;   // 600000
  const int L = in_sizes[11];      // 10
  const int nb = (N + 63) / 64;    // 782 buckets

  const int* srcv = ei;
  const int* dstv = ei + E;

  char* ws = (char*)d_ws;
  size_t off = 0;
  auto alloc = [&](size_t bytes) -> void* {
    void* p = ws + off;
    off = (off + bytes + 255) & ~(size_t)255;
    return p;
  };
  int* bcnt    = (int*)alloc((size_t)MAXB * 4);
  int* bucketA = (int*)alloc((size_t)nb * BCAP * 4);
  int* srcsS   = (int*)alloc((size_t)nb * BCAP * 4);
  int* srcsPad = (int*)alloc((size_t)nb * 64 * 16 * 4);
  int* degE    = (int*)alloc((size_t)nb * 64 * 4);
  int* ebegA   = (int*)alloc((size_t)nb * 64 * 4);
  unsigned short* xb   = (unsigned short*)alloc((size_t)(N + 1) * 128 * 2);
  unsigned short* aggO = (unsigned short*)alloc((size_t)N * 128 * 2);
  unsigned short* h1   = (unsigned short*)alloc((size_t)(N + 1) * 128 * 2);
  unsigned short* h2   = (unsigned short*)alloc((size_t)(N + 1) * 128 * 2);
  unsigned short* h3   = (unsigned short*)alloc((size_t)N * 128 * 2);
  unsigned short* W0T  = (unsigned short*)alloc(128 * 128 * 2);
  unsigned short* W1T  = (unsigned short*)alloc(128 * 128 * 2);
  unsigned short* W2T  = (unsigned short*)alloc(128 * 128 * 2);
  unsigned short* Wm1T = (unsigned short*)alloc(256 * 128 * 2);
  unsigned short* Wm2T = (unsigned short*)alloc(16 * 256 * 2);
  (void)ws_size; (void)n_in; (void)out_size;

  const int tpb = 256;
  int n8 = N * 16;
  prep_all<<<dim3((n8 + tpb - 1) / tpb), dim3(tpb), 0, stream>>>(
      W0, W1, W2, Wm1, Wm2, W0T, W1T, W2T, Wm1T, Wm2T, x, xb, n8, bcnt, h1, h2, N);

  const int nbin = 128;
  int per = (E + nbin - 1) / nbin;
  bin_edges<<<dim3(nbin), dim3(tpb), 0, stream>>>(srcv, dstv, E, per, bcnt, bucketA, nb);
  sort_buckets<<<dim3(nb), dim3(tpb), 0, stream>>>(bcnt, bucketA, srcsS, srcsPad, degE, ebegA, N);

  dim3 agrid((N + 15) / 16);   // 3125 blocks, 16 nodes each
  dim3 ggrid(nb);              // 782 x 64-row GEMM tiles

  agg_kernel<<<agrid, dim3(tpb), 0, stream>>>((const uint4*)xb, srcsPad, srcsS, degE, ebegA, (uint4*)aggO, N);
  gemm_relu<<<ggrid, dim3(tpb), 0, stream>>>(aggO, W0T, b0, h1, N);
  agg_kernel<<<agrid, dim3(tpb), 0, stream>>>((const uint4*)h1, srcsPad, srcsS, degE, ebegA, (uint4*)aggO, N);
  gemm_relu<<<ggrid, dim3(tpb), 0, stream>>>(aggO, W1T, b1, h2, N);
  agg_kernel<<<agrid, dim3(tpb), 0, stream>>>((const uint4*)h2, srcsPad, srcsS, degE, ebegA, (uint4*)aggO, N);
  gemm_relu<<<ggrid, dim3(tpb), 0, stream>>>(aggO, W2T, b2, h3, N);
  fused_head<<<ggrid, dim3(tpb), 0, stream>>>(h3, Wm1T, bm1, Wm2T, bm2, out, N, L);
}